// Round 3
// baseline (124.180 us; speedup 1.0000x reference)
//
#include <hip/hip_runtime.h>

// B=131072, P=3, D=128, H=4, DH=32 ; fp32 in/out.
// Round 3: bf16-MFMA fused kernel, LDS-union + clean write path.
//   pre-kernel: pack W_K|W_Q|W_V (384x128) and W_O (128x128) as bf16 MFMA
//               B-fragments into d_ws (131 KB, L2-resident).
//   main kernel (16 batches = 48 rows / block), ONE 48x392 u16 LDS buffer:
//     stage x (bf16) -> regs a-frags -> barrier -> qkv overwrites buffer
//     -> scalar fp32 causal attention (P=3), z written into dead q-col slots
//     -> MFMA out-proj from z slots -> fp32 global stores (L2 write-back).
// mfma_f32_16x16x32_bf16 layouts (learn_hip m89-verified):
//   A: lane l holds A[l&15][(l>>4)*8 + j], j=0..7
//   B: lane l holds B[(l>>4)*8 + j][l&15]
//   C/D: col = l&15, row = (l>>4)*4 + reg

typedef __attribute__((ext_vector_type(8))) __bf16 bf16x8;
typedef __attribute__((ext_vector_type(4))) float f32x4;
typedef __attribute__((ext_vector_type(8))) unsigned short u16x8;
typedef __attribute__((ext_vector_type(4))) unsigned short u16x4;

#define BATCH 131072
#define PP 3
#define DD 128
#define RB 48            // rows per block = 16 batches * 3
#define BB 16
#define THREADS 256
#define QS_STRIDE 392    // u16; 784 B rows: 16B-aligned, stride%32(dw) = 4

#define NFRAG_QKV (24 * 4)   // 24 n-tiles x 4 k-steps
#define NFRAG_WO (8 * 4)
#define QKV_PACK_ELEMS (NFRAG_QKV * 64 * 8)   // 49152 bf16
#define WO_PACK_ELEMS (NFRAG_WO * 64 * 8)     // 16384 bf16

__device__ __forceinline__ unsigned short f2bf(float f) {
    unsigned int u = __float_as_uint(f);
    u = (u + 0x7fffu + ((u >> 16) & 1u)) >> 16;   // RNE
    return (unsigned short)u;
}
__device__ __forceinline__ float bf2f(unsigned short s) {
    return __uint_as_float(((unsigned int)s) << 16);
}

// ---- weight pre-pack --------------------------------------------------------
__global__ __launch_bounds__(256)
void pack_weights(const float* __restrict__ Wk, const float* __restrict__ Wq,
                  const float* __restrict__ Wv, const float* __restrict__ Wo,
                  unsigned short* __restrict__ pk)
{
    int e = blockIdx.x * 256 + threadIdx.x;     // 0 .. 65535
    int j = e & 7;
    int lane = (e >> 3) & 63;
    int lr = lane & 15, g = lane >> 4;
    float v;
    if (e < QKV_PACK_ELEMS) {
        int ks = (e >> 9) & 3;
        int nt = e >> 11;                        // 0..23
        int n = nt * 16 + lr;                    // 0..127 k, 128..255 q, 256..383 v
        int k = ks * 32 + g * 8 + j;
        const float* base = (n < 128) ? Wk : (n < 256 ? Wq : Wv);
        v = base[(size_t)(n & 127) * DD + k];
    } else {
        int e2 = e - QKV_PACK_ELEMS;
        int ks = (e2 >> 9) & 3;
        int nt = e2 >> 11;                       // 0..7
        int d = nt * 16 + lr;
        int f = ks * 32 + g * 8 + j;
        v = Wo[(size_t)d * DD + f];
    }
    pk[e] = f2bf(v);
}

// ---- fused attention --------------------------------------------------------
__global__ __launch_bounds__(THREADS)
void attn_mfma(const float* __restrict__ x,
               const unsigned short* __restrict__ wpk,
               float* __restrict__ out)
{
    __shared__ unsigned short buf[RB * QS_STRIDE];   // 37632 B, triple-use

    const int t = threadIdx.x;
    const int wave = t >> 6, lane = t & 63;
    const int lr = lane & 15, g = lane >> 4;
    const size_t row0 = (size_t)blockIdx.x * RB;

    // ---- stage x: 48 rows x 128 fp32 -> bf16, coalesced float4 reads, 8B LDS writes
    {
        const float4* xg = (const float4*)(x + row0 * DD);
        #pragma unroll
        for (int it = 0; it < 6; ++it) {
            int i = t + it * 256;                  // 0..1535
            float4 v = xg[i];
            int row = i >> 5, c = (i & 31) * 4;
            u16x4 b;
            b[0] = f2bf(v.x); b[1] = f2bf(v.y); b[2] = f2bf(v.z); b[3] = f2bf(v.w);
            *(u16x4*)&buf[row * QS_STRIDE + c] = b;
        }
    }
    __syncthreads();

    // ---- pull x A-fragments into registers (frees the buffer for qkv)
    bf16x8 a[3][4];
    #pragma unroll
    for (int m = 0; m < 3; ++m)
        #pragma unroll
        for (int k = 0; k < 4; ++k)
            a[m][k] = *(const bf16x8*)&buf[(m * 16 + lr) * QS_STRIDE + k * 32 + g * 8];
    __syncthreads();

    // ---- Phase A: qkv[48][384] = x[48][128] @ W^T  (wave owns 6 n-tiles)
    {
        const bf16x8* bp = (const bf16x8*)wpk;    // frag (nt*4+k)*64+lane
        const int ntb = wave * 6;
        bf16x8 bcur[4], bnxt[4];
        #pragma unroll
        for (int k = 0; k < 4; ++k) bcur[k] = bp[(ntb * 4 + k) * 64 + lane];

        const f32x4 zero4 = {0.f, 0.f, 0.f, 0.f};
        for (int n6 = 0; n6 < 6; ++n6) {
            int nt = ntb + n6;
            if (n6 < 5) {
                #pragma unroll
                for (int k = 0; k < 4; ++k) bnxt[k] = bp[((nt + 1) * 4 + k) * 64 + lane];
            }
            f32x4 acc[3];
            #pragma unroll
            for (int m = 0; m < 3; ++m) acc[m] = zero4;
            #pragma unroll
            for (int k = 0; k < 4; ++k)
                #pragma unroll
                for (int m = 0; m < 3; ++m)
                    acc[m] = __builtin_amdgcn_mfma_f32_16x16x32_bf16(a[m][k], bcur[k], acc[m], 0, 0, 0);
            #pragma unroll
            for (int m = 0; m < 3; ++m)
                #pragma unroll
                for (int r = 0; r < 4; ++r)
                    buf[(m * 16 + g * 4 + r) * QS_STRIDE + nt * 16 + lr] = f2bf(acc[m][r]);
            if (n6 < 5) {
                #pragma unroll
                for (int k = 0; k < 4; ++k) bcur[k] = bnxt[k];
            }
        }
    }
    __syncthreads();

    // ---- Phase B: causal attention, thread per (batch, head, qpos): 192 threads
    // z overwrites the thread's OWN q-column slot (cols 128+co..+31 of row rq),
    // which no other thread reads -> no intra-phase barrier needed.
    if (t < BB * 4 * PP) {
        const int lb = t / 12;
        const int rem = t % 12;
        const int hd = rem / 3;
        const int q = rem % 3;
        const int rq = lb * 3 + q;
        const int co = hd * 32;

        float qv[32];
        #pragma unroll
        for (int c = 0; c < 4; ++c) {
            u16x8 u = *(const u16x8*)&buf[rq * QS_STRIDE + 128 + co + c * 8];
            #pragma unroll
            for (int j = 0; j < 8; ++j) qv[c * 8 + j] = bf2f(u[j]);
        }
        float sc[3];
        float mx = -1e30f;
        #pragma unroll
        for (int p = 0; p < 3; ++p) {
            if (p <= q) {
                float s = 0.f;
                #pragma unroll
                for (int c = 0; c < 4; ++c) {
                    u16x8 u = *(const u16x8*)&buf[(lb * 3 + p) * QS_STRIDE + co + c * 8];
                    #pragma unroll
                    for (int j = 0; j < 8; ++j) s += bf2f(u[j]) * qv[c * 8 + j];
                }
                s *= 0.17677669529663687f;        // 1/sqrt(32)
                sc[p] = s;
                mx = fmaxf(mx, s);
            }
        }
        float l = 0.f;
        #pragma unroll
        for (int p = 0; p < 3; ++p)
            if (p <= q) { sc[p] = __expf(sc[p] - mx); l += sc[p]; }
        const float inv = 1.f / l;

        #pragma unroll
        for (int c = 0; c < 4; ++c) {
            float z[8];
            #pragma unroll
            for (int j = 0; j < 8; ++j) z[j] = 0.f;
            #pragma unroll
            for (int p = 0; p < 3; ++p) {
                if (p <= q) {
                    u16x8 u = *(const u16x8*)&buf[(lb * 3 + p) * QS_STRIDE + 256 + co + c * 8];
                    #pragma unroll
                    for (int j = 0; j < 8; ++j) z[j] += sc[p] * bf2f(u[j]);
                }
            }
            u16x8 o;
            #pragma unroll
            for (int j = 0; j < 8; ++j) o[j] = f2bf(z[j] * inv);
            *(u16x8*)&buf[rq * QS_STRIDE + 128 + co + c * 8] = o;  // own q-slot
        }
    }
    __syncthreads();

    // ---- Phase C: out[48][128] = z[48][128] @ Wo^T  (z lives at col offset 128)
    {
        bf16x8 az[3][4];
        #pragma unroll
        for (int m = 0; m < 3; ++m)
            #pragma unroll
            for (int k = 0; k < 4; ++k)
                az[m][k] = *(const bf16x8*)&buf[(m * 16 + lr) * QS_STRIDE + 128 + k * 32 + g * 8];

        const bf16x8* wop = (const bf16x8*)(wpk + QKV_PACK_ELEMS);
        const f32x4 zero4 = {0.f, 0.f, 0.f, 0.f};
        #pragma unroll
        for (int n2 = 0; n2 < 2; ++n2) {
            int nt = wave * 2 + n2;
            bf16x8 b[4];
            #pragma unroll
            for (int k = 0; k < 4; ++k) b[k] = wop[(nt * 4 + k) * 64 + lane];
            f32x4 acc[3];
            #pragma unroll
            for (int m = 0; m < 3; ++m) acc[m] = zero4;
            #pragma unroll
            for (int k = 0; k < 4; ++k)
                #pragma unroll
                for (int m = 0; m < 3; ++m)
                    acc[m] = __builtin_amdgcn_mfma_f32_16x16x32_bf16(az[m][k], b[k], acc[m], 0, 0, 0);
            #pragma unroll
            for (int m = 0; m < 3; ++m)
                #pragma unroll
                for (int r = 0; r < 4; ++r) {
                    size_t rg = row0 + (size_t)(m * 16 + g * 4 + r);
                    out[rg * DD + nt * 16 + lr] = acc[m][r];   // L2 write-back merges lines
                }
        }
    }
}

extern "C" void kernel_launch(void* const* d_in, const int* in_sizes, int n_in,
                              void* d_out, int out_size, void* d_ws, size_t ws_size,
                              hipStream_t stream) {
    const float* x  = (const float*)d_in[0];
    const float* Wk = (const float*)d_in[1];
    const float* Wq = (const float*)d_in[2];
    const float* Wv = (const float*)d_in[3];
    const float* Wo = (const float*)d_in[4];
    float* out = (float*)d_out;
    unsigned short* pk = (unsigned short*)d_ws;   // needs 131072 B

    pack_weights<<<(QKV_PACK_ELEMS + WO_PACK_ELEMS) / 256, 256, 0, stream>>>(Wk, Wq, Wv, Wo, pk);

    const int grid = BATCH * PP / RB;   // 8192
    attn_mfma<<<grid, THREADS, 0, stream>>>(x, pk, out);
}